// Round 10
// baseline (165.935 us; speedup 1.0000x reference)
//
#include <hip/hip_runtime.h>
#include <math.h>

#define BDIM 2
#define NSEQ 2048
#define DMODEL 512
#define NH 8
#define DH 64
#define INNER (NH * DH)          // 512
#define QKV_COLS (3 * INNER)     // 1536
#define MROWS (BDIM * NSEQ)      // 4096
#define C2 0.180336879f          // 64^-0.5 * log2(e)  (folded into Q at GEMM1)

typedef short bf16x8 __attribute__((ext_vector_type(8)));
typedef float f32x4 __attribute__((ext_vector_type(4)));

static __device__ __forceinline__ unsigned short f2bf(float f) {
    unsigned int u = __float_as_uint(f);
    unsigned int r = (u + 0x7FFFu + ((u >> 16) & 1u)) >> 16;
    return (unsigned short)r;
}
static __device__ __forceinline__ unsigned int pack2bf(float a, float b) {
    unsigned int ua = (__float_as_uint(a) + 0x8000u) >> 16;
    unsigned int ub = (__float_as_uint(b) + 0x8000u) & 0xFFFF0000u;
    return ub | ua;
}

// Async global->LDS, 16B per lane. Dest must be wave-uniform base + lane*16.
static __device__ __forceinline__ void gl_lds16(const unsigned short* g, short* l) {
    __builtin_amdgcn_global_load_lds(
        (const __attribute__((address_space(1))) unsigned int*)(g),
        (__attribute__((address_space(3))) unsigned int*)(l),
        16, 0, 0);
}

// ---------------------------------------------------------------------------
// conv_all: blocks 0..511 convert X fp32 -> bf16; 512..703 transpose Wqkv;
// 704..767 transpose Wout.
// ---------------------------------------------------------------------------
__global__ __launch_bounds__(256) void conv_all_kernel(
    const float* __restrict__ X,
    const float* __restrict__ Wqkv, const float* __restrict__ Wout,
    unsigned short* __restrict__ Xb,
    unsigned short* __restrict__ wqt, unsigned short* __restrict__ wot)
{
    const int t = blockIdx.x, tid = threadIdx.x;
    if (t < 512) {
        const float4* sp = (const float4*)(X + (size_t)t * 4096);
        unsigned short* dp = Xb + (size_t)t * 4096;
#pragma unroll
        for (int i = 0; i < 4; ++i) {
            float4 v = sp[i * 256 + tid];
            uint2 o;
            o.x = pack2bf(v.x, v.y);
            o.y = pack2bf(v.z, v.w);
            *(uint2*)(dp + (size_t)(i * 256 + tid) * 4) = o;
        }
        return;
    }
    __shared__ float T[64][65];
    const float* W; unsigned short* Wt; int R, C, c0, r0;
    if (t < 704) {
        const int u = t - 512;
        W = Wqkv; Wt = wqt; R = DMODEL; C = QKV_COLS;
        c0 = (u % 24) * 64; r0 = (u / 24) * 64;
    } else {
        const int u = t - 704;
        W = Wout; Wt = wot; R = INNER; C = DMODEL;
        c0 = (u & 7) * 64; r0 = (u >> 3) * 64;
    }
    const int tx = tid & 15, ty = tid >> 4;
#pragma unroll
    for (int i = 0; i < 4; ++i) {
        const int r = ty + i * 16;
        float4 v = *(const float4*)(W + (size_t)(r0 + r) * C + c0 + tx * 4);
        T[r][tx * 4 + 0] = v.x; T[r][tx * 4 + 1] = v.y;
        T[r][tx * 4 + 2] = v.z; T[r][tx * 4 + 3] = v.w;
    }
    __syncthreads();
#pragma unroll
    for (int i = 0; i < 4; ++i) {
        const int cc = ty + i * 16;
        ushort4 o;
        o.x = f2bf(T[tx * 4 + 0][cc]);
        o.y = f2bf(T[tx * 4 + 1][cc]);
        o.z = f2bf(T[tx * 4 + 2][cc]);
        o.w = f2bf(T[tx * 4 + 3][cc]);
        *(ushort4*)(Wt + (size_t)(c0 + cc) * R + r0 + tx * 4) = o;
    }
}

// ---------------------------------------------------------------------------
// GEMM1: Xb bf16 [4096,512] @ wqt[1536,512]^T. 2-phase double-buffered
// global_load_lds pipeline. Outputs: Q row-major (pre-scaled by C2);
// K,V fragment-linear.
// ---------------------------------------------------------------------------
__global__ __launch_bounds__(256) void gemm_qkv_kernel(
    const unsigned short* __restrict__ Xb, const unsigned short* __restrict__ Bt,
    unsigned short* __restrict__ Qb, unsigned short* __restrict__ Kf,
    unsigned short* __restrict__ Vf)
{
    __shared__ short Smem[24576];            // 48KB: 2 x (A 128x64 | B 64x64)

    const int tid = threadIdx.x;
    const int w = tid >> 6, lane = tid & 63;
    const int lo = lane & 15, quad = lane >> 4;
    const int wm = (w & 1) * 64, wn = (w >> 1) * 32;

    const int l = blockIdx.x;
    const int xcd = l & 7, p = l >> 3;
    const int mi = (xcd >> 1) * 8 + p / 12;   // 0..31
    const int ni = (xcd & 1) * 12 + p % 12;   // 0..23
    const int m0 = mi * 128, n0 = ni * 64;

    f32x4 acc[4][2];
#pragma unroll
    for (int i = 0; i < 4; ++i)
#pragma unroll
        for (int j = 0; j < 2; ++j) acc[i][j] = (f32x4)0.0f;

    auto stage = [&](int buf, int k0) {
        short* SA = Smem + buf * 12288;
        short* SB = SA + 8192;
#pragma unroll
        for (int it = 0; it < 4; ++it) {
            const int idx = it * 2048 + tid * 8;
            gl_lds16(Xb + (size_t)(m0 + (idx >> 6)) * DMODEL + k0 + (idx & 63),
                     SA + idx);
        }
#pragma unroll
        for (int it = 0; it < 2; ++it) {
            const int idx = it * 2048 + tid * 8;
            gl_lds16(Bt + (size_t)(n0 + (idx >> 6)) * DMODEL + k0 + (idx & 63),
                     SB + idx);
        }
    };

    stage(0, 0);
    __syncthreads();                          // vmcnt(0) drain: buf0 ready
    int cur = 0;
    for (int k0 = 0; k0 < DMODEL; k0 += 64) {
        if (k0 + 64 < DMODEL) stage(cur ^ 1, k0 + 64);
        short* SA = Smem + cur * 12288;
        short* SB = SA + 8192;
#pragma unroll
        for (int kc = 0; kc < 2; ++kc) {
            bf16x8 af[4], bf_[2];
#pragma unroll
            for (int mt = 0; mt < 4; ++mt)
                af[mt] = *(const bf16x8*)&SA[(wm + mt * 16 + lo) * 64 + kc * 32 + quad * 8];
#pragma unroll
            for (int nt = 0; nt < 2; ++nt)
                bf_[nt] = *(const bf16x8*)&SB[(wn + nt * 16 + lo) * 64 + kc * 32 + quad * 8];
#pragma unroll
            for (int mt = 0; mt < 4; ++mt)
#pragma unroll
                for (int nt = 0; nt < 2; ++nt)
                    acc[mt][nt] = __builtin_amdgcn_mfma_f32_16x16x32_bf16(
                        af[mt], bf_[nt], acc[mt][nt], 0, 0, 0);
        }
        __syncthreads();                      // next-tile loads landed; reads done
        cur ^= 1;
    }

    const int which = n0 >> 9;             // 0=Q 1=K 2=V
    const int h0 = (n0 & 511) >> 6;
    const int bb = m0 >> 11, nn0 = m0 & 2047;
    const int jt0 = nn0 >> 6;

    if (which == 0) {
        short (*Cs)[72] = (short (*)[72])Smem;
#pragma unroll
        for (int mt = 0; mt < 4; ++mt)
#pragma unroll
            for (int nt = 0; nt < 2; ++nt)
#pragma unroll
                for (int r = 0; r < 4; ++r)
                    Cs[wm + mt * 16 + quad * 4 + r][wn + nt * 16 + lo] =
                        (short)f2bf(acc[mt][nt][r] * C2);   // fold softmax scale
        __syncthreads();
        unsigned short* dst0 = Qb + ((size_t)(bb * NH + h0) * NSEQ + nn0) * DH;
#pragma unroll
        for (int it = 0; it < 4; ++it) {
            const int lin = it * 256 + tid;
            const int row = lin >> 3, c = (lin & 7) * 8;
            *(int4*)(dst0 + (size_t)row * DH + c) = *(const int4*)&Cs[row][c];
        }
    } else if (which == 1) {
        short (*Cs)[72] = (short (*)[72])Smem;   // [row j][col d]
#pragma unroll
        for (int mt = 0; mt < 4; ++mt)
#pragma unroll
            for (int nt = 0; nt < 2; ++nt)
#pragma unroll
                for (int r = 0; r < 4; ++r)
                    Cs[wm + mt * 16 + quad * 4 + r][wn + nt * 16 + lo] =
                        (short)f2bf(acc[mt][nt][r]);
        __syncthreads();
        unsigned short* dst0 = Kf + (size_t)(bb * NH + h0) * NSEQ * DH +
                               (size_t)jt0 * 4096;
#pragma unroll
        for (int it = 0; it < 4; ++it) {
            const int u = it * 256 + tid;
            const int tile = u >> 9, v = u & 511;
            const int f = v >> 6, ln = v & 63;
            const int row = tile * 64 + (f >> 1) * 16 + (ln & 15);
            const int col = (f & 1) * 32 + (ln >> 4) * 8;
            *(int4*)(dst0 + (size_t)tile * 4096 + f * 512 + ln * 8) =
                *(const int4*)&Cs[row][col];
        }
    } else {
        short (*Cs)[136] = (short (*)[136])Smem;  // [d][local j]
#pragma unroll
        for (int mt = 0; mt < 4; ++mt)
#pragma unroll
            for (int nt = 0; nt < 2; ++nt)
#pragma unroll
                for (int r = 0; r < 4; ++r)
                    Cs[wn + nt * 16 + lo][wm + mt * 16 + quad * 4 + r] =
                        (short)f2bf(acc[mt][nt][r]);
        __syncthreads();
        unsigned short* dst0 = Vf + (size_t)(bb * NH + h0) * NSEQ * DH +
                               (size_t)jt0 * 4096;
#pragma unroll
        for (int it = 0; it < 4; ++it) {
            const int u = it * 256 + tid;
            const int tile = u >> 9, v = u & 511;
            const int f = v >> 6, ln = v & 63;
            const int d = (f >> 1) * 16 + (ln & 15);
            const int jl = tile * 64 + (f & 1) * 32 + (ln >> 4) * 8;
            *(int4*)(dst0 + (size_t)tile * 4096 + f * 512 + ln * 8) =
                *(const int4*)&Cs[d][jl];
        }
    }
}

// ---------------------------------------------------------------------------
// Flash attention (causal). Round-7 version (known-good).
// ---------------------------------------------------------------------------
__global__ __launch_bounds__(256, 3) void flash_kernel(
    const unsigned short* __restrict__ Qb, const unsigned short* __restrict__ Kf,
    const unsigned short* __restrict__ Vf, float* __restrict__ Pml,
    unsigned short* __restrict__ Po)
{
    __shared__ short Pl[4][2][16][72];   // [wave][tile][q][j] (+pad)

    const int tid = threadIdx.x;
    const int w = tid >> 6, lane = tid & 63;
    const int lo = lane & 15, quad = lane >> 4;
    const int hb = blockIdx.x;
    const int h = hb & 7, bb = hb >> 3;              // per-head XCD affinity
    const int sp = blockIdx.z;
    const int qraw = blockIdx.y * 4 + w;             // 0..63
    const int qw = (sp & 1) ? 63 - qraw : qraw;
    const int qtA = qw * 2;

    const unsigned short* Qg = Qb + (size_t)(bb * NH + h) * NSEQ * DH;
    const unsigned short* Kg = Kf + (size_t)(bb * NH + h) * NSEQ * DH;
    const unsigned short* Vg = Vf + (size_t)(bb * NH + h) * NSEQ * DH;

    const unsigned short* qpA = Qg + (size_t)(qtA * 16 + lo) * DH + quad * 8;
    const bf16x8 aqA0 = *(const bf16x8*)qpA;
    const bf16x8 aqA1 = *(const bf16x8*)(qpA + 32);
    const bf16x8 aqB0 = *(const bf16x8*)(qpA + 1024);
    const bf16x8 aqB1 = *(const bf16x8*)(qpA + 1024 + 32);

    const int jd = qw >> 1;
    const int nIter = (jd >= sp) ? ((jd - sp) / 3 + 1) : 0;
    const int qrelA = (qtA & 3) * 16 + lo;

    f32x4 OA[4], OB[4];
#pragma unroll
    for (int dt = 0; dt < 4; ++dt) { OA[dt] = (f32x4)0.0f; OB[dt] = (f32x4)0.0f; }
    f32x4 lAv = (f32x4)0.0f, lBv = (f32x4)0.0f;

    for (int it = 0; it < nIter; ++it) {
        const int jb = sp + it * 3;
        const size_t base = (size_t)jb * 4096 + lane * 8;

        int4 kf8[8], vf8[8];
#pragma unroll
        for (int f = 0; f < 8; ++f) kf8[f] = *(const int4*)(Kg + base + f * 512);
#pragma unroll
        for (int f = 0; f < 8; ++f) vf8[f] = *(const int4*)(Vg + base + f * 512);

        f32x4 sA[4], sB[4];
#pragma unroll
        for (int nt = 0; nt < 4; ++nt) { sA[nt] = (f32x4)0.0f; sB[nt] = (f32x4)0.0f; }
        __builtin_amdgcn_s_setprio(1);
#pragma unroll
        for (int kc = 0; kc < 2; ++kc) {
            const bf16x8 aqa = kc ? aqA1 : aqA0;
            const bf16x8 aqb = kc ? aqB1 : aqB0;
#pragma unroll
            for (int nt = 0; nt < 4; ++nt) {
                const bf16x8 kfr = *(const bf16x8*)&kf8[nt * 2 + kc];
                sA[nt] = __builtin_amdgcn_mfma_f32_16x16x32_bf16(kfr, aqa, sA[nt], 0, 0, 0);
                sB[nt] = __builtin_amdgcn_mfma_f32_16x16x32_bf16(kfr, aqb, sB[nt], 0, 0, 0);
            }
        }
        __builtin_amdgcn_s_setprio(0);

        if (jb == jd) {
#pragma unroll
            for (int nt = 0; nt < 4; ++nt)
#pragma unroll
                for (int r = 0; r < 4; ++r) {
                    const int jrel = nt * 16 + quad * 4 + r;
                    if (jrel > qrelA) sA[nt][r] = -1e30f;
                    if (jrel > qrelA + 16) sB[nt][r] = -1e30f;
                }
        }

#pragma unroll
        for (int nt = 0; nt < 4; ++nt)
#pragma unroll
            for (int r = 0; r < 4; ++r) {
                sA[nt][r] = __builtin_exp2f(sA[nt][r]);   // Q pre-scaled by C2
                sB[nt][r] = __builtin_exp2f(sB[nt][r]);
            }
#pragma unroll
        for (int nt = 0; nt < 4; ++nt) {
            lAv += sA[nt];                                // 4 independent chains
            lBv += sB[nt];
        }

#pragma unroll
        for (int nt = 0; nt < 4; ++nt) {
            int2 wa = make_int2((int)pack2bf(sA[nt][0], sA[nt][1]),
                                (int)pack2bf(sA[nt][2], sA[nt][3]));
            int2 wb = make_int2((int)pack2bf(sB[nt][0], sB[nt][1]),
                                (int)pack2bf(sB[nt][2], sB[nt][3]));
            *(int2*)&Pl[w][0][lo][nt * 16 + quad * 4] = wa;
            *(int2*)&Pl[w][1][lo][nt * 16 + quad * 4] = wb;
        }
        const bf16x8 pbA0 = *(const bf16x8*)&Pl[w][0][lo][quad * 8];
        const bf16x8 pbA1 = *(const bf16x8*)&Pl[w][0][lo][32 + quad * 8];
        const bf16x8 pbB0 = *(const bf16x8*)&Pl[w][1][lo][quad * 8];
        const bf16x8 pbB1 = *(const bf16x8*)&Pl[w][1][lo][32 + quad * 8];

        __builtin_amdgcn_s_setprio(1);
#pragma unroll
        for (int kc = 0; kc < 2; ++kc) {
            const bf16x8 pa = kc ? pbA1 : pbA0;
            const bf16x8 pb = kc ? pbB1 : pbB0;
#pragma unroll
            for (int dt = 0; dt < 4; ++dt) {
                const bf16x8 vfr = *(const bf16x8*)&vf8[dt * 2 + kc];
                OA[dt] = __builtin_amdgcn_mfma_f32_16x16x32_bf16(vfr, pa, OA[dt], 0, 0, 0);
                OB[dt] = __builtin_amdgcn_mfma_f32_16x16x32_bf16(vfr, pb, OB[dt], 0, 0, 0);
            }
        }
        __builtin_amdgcn_s_setprio(0);
    }

    float lA = (lAv[0] + lAv[1]) + (lAv[2] + lAv[3]);
    float lB = (lBv[0] + lBv[1]) + (lBv[2] + lBv[3]);
    lA += __shfl_xor(lA, 16); lA += __shfl_xor(lA, 32);
    lB += __shfl_xor(lB, 16); lB += __shfl_xor(lB, 32);

    const int pidx = (hb * 64 + qw) * 3 + sp;
    if (quad == 0) {
        Pml[(size_t)pidx * 32 + lo] = lA;
        Pml[(size_t)pidx * 32 + 16 + lo] = lB;
    }
    const float invA = (lA > 0.0f) ? 1.0f / lA : 0.0f;
    const float invB = (lB > 0.0f) ? 1.0f / lB : 0.0f;
    unsigned short* po = Po + (size_t)pidx * 2048;
#pragma unroll
    for (int dt = 0; dt < 4; ++dt) {
        uint2 va, vb;
        va.x = pack2bf(OA[dt][0] * invA, OA[dt][1] * invA);
        va.y = pack2bf(OA[dt][2] * invA, OA[dt][3] * invA);
        vb.x = pack2bf(OB[dt][0] * invB, OB[dt][1] * invB);
        vb.y = pack2bf(OB[dt][2] * invB, OB[dt][3] * invB);
        *(uint2*)(po + lo * 64 + quad * 4 + dt * 16) = va;
        *(uint2*)(po + (16 + lo) * 64 + quad * 4 + dt * 16) = vb;
    }
}

// ---------------------------------------------------------------------------
// Combine the three j-split partials -> attnb [b][n][h*64+d] bf16.
// ---------------------------------------------------------------------------
__global__ __launch_bounds__(256) void combine_kernel(
    const float* __restrict__ Pml, const unsigned short* __restrict__ Po,
    unsigned short* __restrict__ attnb)
{
    const int g = blockIdx.x;            // hb*64 + qw
    const int hb = g >> 6, qw = g & 63;
    const int h = hb & 7, bb = hb >> 3;
    const int tid = threadIdx.x;
    const int row = tid >> 3;            // 0..31
    const int d0 = (tid & 7) * 8;

    const float l0 = Pml[(size_t)(g * 3 + 0) * 32 + row];
    const float l1 = Pml[(size_t)(g * 3 + 1) * 32 + row];
    const float l2 = Pml[(size_t)(g * 3 + 2) * 32 + row];
    const float inv = 1.0f / (l0 + l1 + l2);
    const float c0 = l0 * inv, c1 = l1 * inv, c2 = l2 * inv;

    const unsigned short* p0 = Po + (size_t)(g * 3 + 0) * 2048 + row * 64 + d0;
    const unsigned short* p1 = p0 + 2048;
    const unsigned short* p2 = p1 + 2048;
    unsigned short sa[8], sb[8], sc[8], so[8];
    *(int4*)&sa[0] = *(const int4*)p0;
    *(int4*)&sb[0] = *(const int4*)p1;
    *(int4*)&sc[0] = *(const int4*)p2;
#pragma unroll
    for (int i = 0; i < 8; ++i) {
        float fa = __uint_as_float((unsigned int)sa[i] << 16);
        float fb = __uint_as_float((unsigned int)sb[i] << 16);
        float fc = __uint_as_float((unsigned int)sc[i] << 16);
        so[i] = f2bf(fa * c0 + fb * c1 + fc * c2);
    }
    unsigned short* dst = attnb + ((size_t)bb * NSEQ + qw * 32 + row) * INNER + h * DH + d0;
    *(int4*)dst = *(const int4*)&so[0];
}

// ---------------------------------------------------------------------------
// GEMM2: attnb[4096,512] @ wot[512,512]^T + bias -> out fp32. 2-phase
// double-buffered pipeline, 128x64 tiles (round-7 version).
// ---------------------------------------------------------------------------
__global__ __launch_bounds__(256) void gemm_out_kernel(
    const unsigned short* __restrict__ A, const unsigned short* __restrict__ Bt,
    const float* __restrict__ bias, float* __restrict__ out)
{
    __shared__ short Smem[24576];            // 48KB: 2 x (A 128x64 | B 64x64)

    const int tid = threadIdx.x;
    const int w = tid >> 6, lane = tid & 63;
    const int lo = lane & 15, quad = lane >> 4;
    const int wm = (w & 1) * 64, wn = (w >> 1) * 32;

    const int l = blockIdx.x;
    const int xcd = l & 7, p = l >> 3;
    const int mi = (xcd >> 1) * 8 + (p >> 2);   // 0..31
    const int ni = (xcd & 1) * 4 + (p & 3);     // 0..7
    const int m0 = mi * 128, n0 = ni * 64;

    f32x4 acc[4][2];
#pragma unroll
    for (int i = 0; i < 4; ++i)
#pragma unroll
        for (int j = 0; j < 2; ++j) acc[i][j] = (f32x4)0.0f;

    auto stage = [&](int buf, int k0) {
        short* SA = Smem + buf * 12288;
        short* SB = SA + 8192;
#pragma unroll
        for (int it = 0; it < 4; ++it) {
            const int idx = it * 2048 + tid * 8;
            gl_lds16(A + (size_t)(m0 + (idx >> 6)) * INNER + k0 + (idx & 63),
                     SA + idx);
        }
#pragma unroll
        for (int it = 0; it < 2; ++it) {
            const int idx = it * 2048 + tid * 8;
            gl_lds16(Bt + (size_t)(n0 + (idx >> 6)) * INNER + k0 + (idx & 63),
                     SB + idx);
        }
    };

    stage(0, 0);
    __syncthreads();
    int cur = 0;
    for (int k0 = 0; k0 < INNER; k0 += 64) {
        if (k0 + 64 < INNER) stage(cur ^ 1, k0 + 64);
        short* SA = Smem + cur * 12288;
        short* SB = SA + 8192;
#pragma unroll
        for (int kc = 0; kc < 2; ++kc) {
            bf16x8 af[4], bf_[2];
#pragma unroll
            for (int mt = 0; mt < 4; ++mt)
                af[mt] = *(const bf16x8*)&SA[(wm + mt * 16 + lo) * 64 + kc * 32 + quad * 8];
#pragma unroll
            for (int nt = 0; nt < 2; ++nt)
                bf_[nt] = *(const bf16x8*)&SB[(wn + nt * 16 + lo) * 64 + kc * 32 + quad * 8];
#pragma unroll
            for (int mt = 0; mt < 4; ++mt)
#pragma unroll
                for (int nt = 0; nt < 2; ++nt)
                    acc[mt][nt] = __builtin_amdgcn_mfma_f32_16x16x32_bf16(
                        af[mt], bf_[nt], acc[mt][nt], 0, 0, 0);
        }
        __syncthreads();
        cur ^= 1;
    }

#pragma unroll
    for (int mt = 0; mt < 4; ++mt) {
        const int gm0 = m0 + wm + mt * 16 + quad * 4;
#pragma unroll
        for (int nt = 0; nt < 2; ++nt) {
            const int gc = n0 + wn + nt * 16 + lo;
            const float b = bias[gc];
#pragma unroll
            for (int r = 0; r < 4; ++r)
                out[(size_t)(gm0 + r) * DMODEL + gc] = acc[mt][nt][r] + b;
        }
    }
}

// ---------------------------------------------------------------------------
// DIAGNOSTIC THIS ROUND: EVERY kernel dispatched twice (all are idempotent;
// output bit-identical). dur_2x - 118.5 = sum of warm kernel durations;
// 118.5 - that sum = aggregate boundary/launch/cold overhead. This cleanly
// separates "gemm_qkv is huge" from "dispatch overhead is huge".
// ---------------------------------------------------------------------------
extern "C" void kernel_launch(void* const* d_in, const int* in_sizes, int n_in,
                              void* d_out, int out_size, void* d_ws, size_t ws_size,
                              hipStream_t stream) {
    const float* x    = (const float*)d_in[0];
    const float* Wqkv = (const float*)d_in[2];
    const float* Wout = (const float*)d_in[3];
    const float* bout = (const float*)d_in[4];
    float* out = (float*)d_out;

    unsigned short* wsS  = (unsigned short*)d_ws;
    unsigned short* wqt  = wsS;                                  // 768K shorts
    unsigned short* wot  = wqt + (size_t)QKV_COLS * DMODEL;      // 256K
    unsigned short* Qb   = wot + (size_t)DMODEL * INNER;         // 2M
    unsigned short* Kf   = Qb  + (size_t)BDIM * NH * NSEQ * DH;  // 2M
    unsigned short* Vf   = Kf  + (size_t)BDIM * NH * NSEQ * DH;  // 2M
    unsigned short* Po   = Vf  + (size_t)BDIM * NH * NSEQ * DH;  // 6M
    float* Pml = (float*)(Po + (size_t)3072 * 2048);             // 96K floats
    unsigned short* attnb = (unsigned short*)(Pml + 3072 * 32);  // 2M
    unsigned short* Xb   = attnb + (size_t)MROWS * INNER;        // 2M

    conv_all_kernel<<<768, 256, 0, stream>>>(x, Wqkv, Wout, Xb, wqt, wot);
    conv_all_kernel<<<768, 256, 0, stream>>>(x, Wqkv, Wout, Xb, wqt, wot);      // diag dup
    gemm_qkv_kernel<<<768, 256, 0, stream>>>(Xb, wqt, Qb, Kf, Vf);
    gemm_qkv_kernel<<<768, 256, 0, stream>>>(Xb, wqt, Qb, Kf, Vf);              // diag dup
    flash_kernel<<<dim3(NH * BDIM, 16, 3), 256, 0, stream>>>(Qb, Kf, Vf, Pml, Po);
    flash_kernel<<<dim3(NH * BDIM, 16, 3), 256, 0, stream>>>(Qb, Kf, Vf, Pml, Po);  // diag dup
    combine_kernel<<<NH * BDIM * 64, 256, 0, stream>>>(Pml, Po, attnb);
    combine_kernel<<<NH * BDIM * 64, 256, 0, stream>>>(Pml, Po, attnb);         // diag dup
    gemm_out_kernel<<<256, 256, 0, stream>>>(attnb, wot, bout, out);
    gemm_out_kernel<<<256, 256, 0, stream>>>(attnb, wot, bout, out);            // diag dup
}

// Round 11
// 117.784 us; speedup vs baseline: 1.4088x; 1.4088x over previous
//
#include <hip/hip_runtime.h>
#include <math.h>

#define BDIM 2
#define NSEQ 2048
#define DMODEL 512
#define NH 8
#define DH 64
#define INNER (NH * DH)          // 512
#define QKV_COLS (3 * INNER)     // 1536
#define MROWS (BDIM * NSEQ)      // 4096
#define C2 0.180336879f          // 64^-0.5 * log2(e)  (folded into Q at GEMM1)

typedef short bf16x8 __attribute__((ext_vector_type(8)));
typedef float f32x4 __attribute__((ext_vector_type(4)));

static __device__ __forceinline__ unsigned short f2bf(float f) {
    unsigned int u = __float_as_uint(f);
    unsigned int r = (u + 0x7FFFu + ((u >> 16) & 1u)) >> 16;
    return (unsigned short)r;
}
static __device__ __forceinline__ unsigned int pack2bf(float a, float b) {
    unsigned int ua = (__float_as_uint(a) + 0x8000u) >> 16;
    unsigned int ub = (__float_as_uint(b) + 0x8000u) & 0xFFFF0000u;
    return ub | ua;
}

// Async global->LDS, 16B per lane. Dest must be wave-uniform base + lane*16.
static __device__ __forceinline__ void gl_lds16(const unsigned short* g, short* l) {
    __builtin_amdgcn_global_load_lds(
        (const __attribute__((address_space(1))) unsigned int*)(g),
        (__attribute__((address_space(3))) unsigned int*)(l),
        16, 0, 0);
}

// ---------------------------------------------------------------------------
// conv_all: blocks 0..511 convert X fp32 -> bf16; 512..703 transpose Wqkv;
// 704..767 transpose Wout.  (unchanged)
// ---------------------------------------------------------------------------
__global__ __launch_bounds__(256) void conv_all_kernel(
    const float* __restrict__ X,
    const float* __restrict__ Wqkv, const float* __restrict__ Wout,
    unsigned short* __restrict__ Xb,
    unsigned short* __restrict__ wqt, unsigned short* __restrict__ wot)
{
    const int t = blockIdx.x, tid = threadIdx.x;
    if (t < 512) {
        const float4* sp = (const float4*)(X + (size_t)t * 4096);
        unsigned short* dp = Xb + (size_t)t * 4096;
#pragma unroll
        for (int i = 0; i < 4; ++i) {
            float4 v = sp[i * 256 + tid];
            uint2 o;
            o.x = pack2bf(v.x, v.y);
            o.y = pack2bf(v.z, v.w);
            *(uint2*)(dp + (size_t)(i * 256 + tid) * 4) = o;
        }
        return;
    }
    __shared__ float T[64][65];
    const float* W; unsigned short* Wt; int R, C, c0, r0;
    if (t < 704) {
        const int u = t - 512;
        W = Wqkv; Wt = wqt; R = DMODEL; C = QKV_COLS;
        c0 = (u % 24) * 64; r0 = (u / 24) * 64;
    } else {
        const int u = t - 704;
        W = Wout; Wt = wot; R = INNER; C = DMODEL;
        c0 = (u & 7) * 64; r0 = (u >> 3) * 64;
    }
    const int tx = tid & 15, ty = tid >> 4;
#pragma unroll
    for (int i = 0; i < 4; ++i) {
        const int r = ty + i * 16;
        float4 v = *(const float4*)(W + (size_t)(r0 + r) * C + c0 + tx * 4);
        T[r][tx * 4 + 0] = v.x; T[r][tx * 4 + 1] = v.y;
        T[r][tx * 4 + 2] = v.z; T[r][tx * 4 + 3] = v.w;
    }
    __syncthreads();
#pragma unroll
    for (int i = 0; i < 4; ++i) {
        const int cc = ty + i * 16;
        ushort4 o;
        o.x = f2bf(T[tx * 4 + 0][cc]);
        o.y = f2bf(T[tx * 4 + 1][cc]);
        o.z = f2bf(T[tx * 4 + 2][cc]);
        o.w = f2bf(T[tx * 4 + 3][cc]);
        *(ushort4*)(Wt + (size_t)(c0 + cc) * R + r0 + tx * 4) = o;
    }
}

// ---------------------------------------------------------------------------
// GEMM1: Xb bf16 [4096,512] @ wqt[1536,512]^T. NEW: 128x128 tile (m93 ladder
// step: halves A re-read traffic, doubles MFMA per staged byte). 384 blocks,
// 2-phase dbuf gl_lds pipeline (64KB LDS -> 2 blocks/CU, 8 waves/CU).
// Waves 2x2: wm=(w&1)*64, wn=(w>>1)*64; acc[4][4]. Epilogue runs the
// verified 64-wide store/copy path once per column-half (each half = one
// head; Q/K/V boundaries are 128-aligned so 'which' is uniform per tile).
// Outputs: Q row-major (pre-scaled by C2); K,V fragment-linear.
// ---------------------------------------------------------------------------
__global__ __launch_bounds__(256) void gemm_qkv_kernel(
    const unsigned short* __restrict__ Xb, const unsigned short* __restrict__ Bt,
    unsigned short* __restrict__ Qb, unsigned short* __restrict__ Kf,
    unsigned short* __restrict__ Vf)
{
    __shared__ short Smem[32768];            // 64KB: 2 x (A 128x64 | B 128x64)

    const int tid = threadIdx.x;
    const int w = tid >> 6, lane = tid & 63;
    const int lo = lane & 15, quad = lane >> 4;
    const int wm = (w & 1) * 64, wn = (w >> 1) * 64;

    const int l = blockIdx.x;                 // 384 blocks
    const int xcd = l & 7, p = l >> 3;        // p 0..47
    const int mi = (xcd >> 1) * 8 + p / 6;    // 0..31
    const int ni = (xcd & 1) * 6 + p % 6;     // 0..11
    const int m0 = mi * 128, n0 = ni * 128;

    f32x4 acc[4][4];
#pragma unroll
    for (int i = 0; i < 4; ++i)
#pragma unroll
        for (int j = 0; j < 4; ++j) acc[i][j] = (f32x4)0.0f;

    auto stage = [&](int buf, int k0) {
        short* SA = Smem + buf * 16384;
        short* SB = SA + 8192;
#pragma unroll
        for (int it = 0; it < 4; ++it) {
            const int idx = it * 2048 + tid * 8;
            gl_lds16(Xb + (size_t)(m0 + (idx >> 6)) * DMODEL + k0 + (idx & 63),
                     SA + idx);
        }
#pragma unroll
        for (int it = 0; it < 4; ++it) {
            const int idx = it * 2048 + tid * 8;
            gl_lds16(Bt + (size_t)(n0 + (idx >> 6)) * DMODEL + k0 + (idx & 63),
                     SB + idx);
        }
    };

    stage(0, 0);
    __syncthreads();                          // vmcnt(0) drain: buf0 ready
    int cur = 0;
    for (int k0 = 0; k0 < DMODEL; k0 += 64) {
        if (k0 + 64 < DMODEL) stage(cur ^ 1, k0 + 64);
        short* SA = Smem + cur * 16384;
        short* SB = SA + 8192;
#pragma unroll
        for (int kc = 0; kc < 2; ++kc) {
            bf16x8 af[4], bf_[4];
#pragma unroll
            for (int mt = 0; mt < 4; ++mt)
                af[mt] = *(const bf16x8*)&SA[(wm + mt * 16 + lo) * 64 + kc * 32 + quad * 8];
#pragma unroll
            for (int nt = 0; nt < 4; ++nt)
                bf_[nt] = *(const bf16x8*)&SB[(wn + nt * 16 + lo) * 64 + kc * 32 + quad * 8];
#pragma unroll
            for (int mt = 0; mt < 4; ++mt)
#pragma unroll
                for (int nt = 0; nt < 4; ++nt)
                    acc[mt][nt] = __builtin_amdgcn_mfma_f32_16x16x32_bf16(
                        af[mt], bf_[nt], acc[mt][nt], 0, 0, 0);
        }
        __syncthreads();                      // next-tile loads landed; reads done
        cur ^= 1;
    }

    const int bb = m0 >> 11, nn0 = m0 & 2047;
    const int jt0 = nn0 >> 6;
    const int which = n0 >> 9;             // uniform across both halves

    // Epilogue per 64-column half. Waves (w>>1)==half own that half's acc.
#pragma unroll
    for (int half = 0; half < 2; ++half) {
        const int n0h = n0 + half * 64;
        const int h0 = (n0h & 511) >> 6;
        __syncthreads();                   // Cs free (prev copy done / K-loop done)

        if (which == 0) {
            short (*Cs)[72] = (short (*)[72])Smem;
            if ((w >> 1) == half) {
#pragma unroll
                for (int mt = 0; mt < 4; ++mt)
#pragma unroll
                    for (int nt = 0; nt < 4; ++nt)
#pragma unroll
                        for (int r = 0; r < 4; ++r)
                            Cs[wm + mt * 16 + quad * 4 + r][nt * 16 + lo] =
                                (short)f2bf(acc[mt][nt][r] * C2);
            }
            __syncthreads();
            unsigned short* dst0 = Qb + ((size_t)(bb * NH + h0) * NSEQ + nn0) * DH;
#pragma unroll
            for (int it = 0; it < 4; ++it) {
                const int lin = it * 256 + tid;
                const int row = lin >> 3, c = (lin & 7) * 8;
                *(int4*)(dst0 + (size_t)row * DH + c) = *(const int4*)&Cs[row][c];
            }
        } else if (which == 1) {
            short (*Cs)[72] = (short (*)[72])Smem;   // [row j][col d]
            if ((w >> 1) == half) {
#pragma unroll
                for (int mt = 0; mt < 4; ++mt)
#pragma unroll
                    for (int nt = 0; nt < 4; ++nt)
#pragma unroll
                        for (int r = 0; r < 4; ++r)
                            Cs[wm + mt * 16 + quad * 4 + r][nt * 16 + lo] =
                                (short)f2bf(acc[mt][nt][r]);
            }
            __syncthreads();
            unsigned short* dst0 = Kf + (size_t)(bb * NH + h0) * NSEQ * DH +
                                   (size_t)jt0 * 4096;
#pragma unroll
            for (int it = 0; it < 4; ++it) {
                const int u = it * 256 + tid;
                const int tile = u >> 9, v = u & 511;
                const int f = v >> 6, ln = v & 63;
                const int row = tile * 64 + (f >> 1) * 16 + (ln & 15);
                const int col = (f & 1) * 32 + (ln >> 4) * 8;
                *(int4*)(dst0 + (size_t)tile * 4096 + f * 512 + ln * 8) =
                    *(const int4*)&Cs[row][col];
            }
        } else {
            short (*Cs)[136] = (short (*)[136])Smem;  // [d][local j]
            if ((w >> 1) == half) {
#pragma unroll
                for (int mt = 0; mt < 4; ++mt)
#pragma unroll
                    for (int nt = 0; nt < 4; ++nt)
#pragma unroll
                        for (int r = 0; r < 4; ++r)
                            Cs[nt * 16 + lo][wm + mt * 16 + quad * 4 + r] =
                                (short)f2bf(acc[mt][nt][r]);
            }
            __syncthreads();
            unsigned short* dst0 = Vf + (size_t)(bb * NH + h0) * NSEQ * DH +
                                   (size_t)jt0 * 4096;
#pragma unroll
            for (int it = 0; it < 4; ++it) {
                const int u = it * 256 + tid;
                const int tile = u >> 9, v = u & 511;
                const int f = v >> 6, ln = v & 63;
                const int d = (f >> 1) * 16 + (ln & 15);
                const int jl = tile * 64 + (f & 1) * 32 + (ln >> 4) * 8;
                *(int4*)(dst0 + (size_t)tile * 4096 + f * 512 + ln * 8) =
                    *(const int4*)&Cs[d][jl];
            }
        }
    }
}

// ---------------------------------------------------------------------------
// Flash attention (causal). Round-7 version (known-good), unchanged.
// ---------------------------------------------------------------------------
__global__ __launch_bounds__(256, 3) void flash_kernel(
    const unsigned short* __restrict__ Qb, const unsigned short* __restrict__ Kf,
    const unsigned short* __restrict__ Vf, float* __restrict__ Pml,
    unsigned short* __restrict__ Po)
{
    __shared__ short Pl[4][2][16][72];   // [wave][tile][q][j] (+pad)

    const int tid = threadIdx.x;
    const int w = tid >> 6, lane = tid & 63;
    const int lo = lane & 15, quad = lane >> 4;
    const int hb = blockIdx.x;
    const int h = hb & 7, bb = hb >> 3;              // per-head XCD affinity
    const int sp = blockIdx.z;
    const int qraw = blockIdx.y * 4 + w;             // 0..63
    const int qw = (sp & 1) ? 63 - qraw : qraw;
    const int qtA = qw * 2;

    const unsigned short* Qg = Qb + (size_t)(bb * NH + h) * NSEQ * DH;
    const unsigned short* Kg = Kf + (size_t)(bb * NH + h) * NSEQ * DH;
    const unsigned short* Vg = Vf + (size_t)(bb * NH + h) * NSEQ * DH;

    const unsigned short* qpA = Qg + (size_t)(qtA * 16 + lo) * DH + quad * 8;
    const bf16x8 aqA0 = *(const bf16x8*)qpA;
    const bf16x8 aqA1 = *(const bf16x8*)(qpA + 32);
    const bf16x8 aqB0 = *(const bf16x8*)(qpA + 1024);
    const bf16x8 aqB1 = *(const bf16x8*)(qpA + 1024 + 32);

    const int jd = qw >> 1;
    const int nIter = (jd >= sp) ? ((jd - sp) / 3 + 1) : 0;
    const int qrelA = (qtA & 3) * 16 + lo;

    f32x4 OA[4], OB[4];
#pragma unroll
    for (int dt = 0; dt < 4; ++dt) { OA[dt] = (f32x4)0.0f; OB[dt] = (f32x4)0.0f; }
    f32x4 lAv = (f32x4)0.0f, lBv = (f32x4)0.0f;

    for (int it = 0; it < nIter; ++it) {
        const int jb = sp + it * 3;
        const size_t base = (size_t)jb * 4096 + lane * 8;

        int4 kf8[8], vf8[8];
#pragma unroll
        for (int f = 0; f < 8; ++f) kf8[f] = *(const int4*)(Kg + base + f * 512);
#pragma unroll
        for (int f = 0; f < 8; ++f) vf8[f] = *(const int4*)(Vg + base + f * 512);

        f32x4 sA[4], sB[4];
#pragma unroll
        for (int nt = 0; nt < 4; ++nt) { sA[nt] = (f32x4)0.0f; sB[nt] = (f32x4)0.0f; }
        __builtin_amdgcn_s_setprio(1);
#pragma unroll
        for (int kc = 0; kc < 2; ++kc) {
            const bf16x8 aqa = kc ? aqA1 : aqA0;
            const bf16x8 aqb = kc ? aqB1 : aqB0;
#pragma unroll
            for (int nt = 0; nt < 4; ++nt) {
                const bf16x8 kfr = *(const bf16x8*)&kf8[nt * 2 + kc];
                sA[nt] = __builtin_amdgcn_mfma_f32_16x16x32_bf16(kfr, aqa, sA[nt], 0, 0, 0);
                sB[nt] = __builtin_amdgcn_mfma_f32_16x16x32_bf16(kfr, aqb, sB[nt], 0, 0, 0);
            }
        }
        __builtin_amdgcn_s_setprio(0);

        if (jb == jd) {
#pragma unroll
            for (int nt = 0; nt < 4; ++nt)
#pragma unroll
                for (int r = 0; r < 4; ++r) {
                    const int jrel = nt * 16 + quad * 4 + r;
                    if (jrel > qrelA) sA[nt][r] = -1e30f;
                    if (jrel > qrelA + 16) sB[nt][r] = -1e30f;
                }
        }

#pragma unroll
        for (int nt = 0; nt < 4; ++nt)
#pragma unroll
            for (int r = 0; r < 4; ++r) {
                sA[nt][r] = __builtin_exp2f(sA[nt][r]);   // Q pre-scaled by C2
                sB[nt][r] = __builtin_exp2f(sB[nt][r]);
            }
#pragma unroll
        for (int nt = 0; nt < 4; ++nt) {
            lAv += sA[nt];                                // 4 independent chains
            lBv += sB[nt];
        }

#pragma unroll
        for (int nt = 0; nt < 4; ++nt) {
            int2 wa = make_int2((int)pack2bf(sA[nt][0], sA[nt][1]),
                                (int)pack2bf(sA[nt][2], sA[nt][3]));
            int2 wb = make_int2((int)pack2bf(sB[nt][0], sB[nt][1]),
                                (int)pack2bf(sB[nt][2], sB[nt][3]));
            *(int2*)&Pl[w][0][lo][nt * 16 + quad * 4] = wa;
            *(int2*)&Pl[w][1][lo][nt * 16 + quad * 4] = wb;
        }
        const bf16x8 pbA0 = *(const bf16x8*)&Pl[w][0][lo][quad * 8];
        const bf16x8 pbA1 = *(const bf16x8*)&Pl[w][0][lo][32 + quad * 8];
        const bf16x8 pbB0 = *(const bf16x8*)&Pl[w][1][lo][quad * 8];
        const bf16x8 pbB1 = *(const bf16x8*)&Pl[w][1][lo][32 + quad * 8];

        __builtin_amdgcn_s_setprio(1);
#pragma unroll
        for (int kc = 0; kc < 2; ++kc) {
            const bf16x8 pa = kc ? pbA1 : pbA0;
            const bf16x8 pb = kc ? pbB1 : pbB0;
#pragma unroll
            for (int dt = 0; dt < 4; ++dt) {
                const bf16x8 vfr = *(const bf16x8*)&vf8[dt * 2 + kc];
                OA[dt] = __builtin_amdgcn_mfma_f32_16x16x32_bf16(vfr, pa, OA[dt], 0, 0, 0);
                OB[dt] = __builtin_amdgcn_mfma_f32_16x16x32_bf16(vfr, pb, OB[dt], 0, 0, 0);
            }
        }
        __builtin_amdgcn_s_setprio(0);
    }

    float lA = (lAv[0] + lAv[1]) + (lAv[2] + lAv[3]);
    float lB = (lBv[0] + lBv[1]) + (lBv[2] + lBv[3]);
    lA += __shfl_xor(lA, 16); lA += __shfl_xor(lA, 32);
    lB += __shfl_xor(lB, 16); lB += __shfl_xor(lB, 32);

    const int pidx = (hb * 64 + qw) * 3 + sp;
    if (quad == 0) {
        Pml[(size_t)pidx * 32 + lo] = lA;
        Pml[(size_t)pidx * 32 + 16 + lo] = lB;
    }
    const float invA = (lA > 0.0f) ? 1.0f / lA : 0.0f;
    const float invB = (lB > 0.0f) ? 1.0f / lB : 0.0f;
    unsigned short* po = Po + (size_t)pidx * 2048;
#pragma unroll
    for (int dt = 0; dt < 4; ++dt) {
        uint2 va, vb;
        va.x = pack2bf(OA[dt][0] * invA, OA[dt][1] * invA);
        va.y = pack2bf(OA[dt][2] * invA, OA[dt][3] * invA);
        vb.x = pack2bf(OB[dt][0] * invB, OB[dt][1] * invB);
        vb.y = pack2bf(OB[dt][2] * invB, OB[dt][3] * invB);
        *(uint2*)(po + lo * 64 + quad * 4 + dt * 16) = va;
        *(uint2*)(po + (16 + lo) * 64 + quad * 4 + dt * 16) = vb;
    }
}

// ---------------------------------------------------------------------------
// Combine the three j-split partials -> attnb [b][n][h*64+d] bf16. Unchanged.
// ---------------------------------------------------------------------------
__global__ __launch_bounds__(256) void combine_kernel(
    const float* __restrict__ Pml, const unsigned short* __restrict__ Po,
    unsigned short* __restrict__ attnb)
{
    const int g = blockIdx.x;            // hb*64 + qw
    const int hb = g >> 6, qw = g & 63;
    const int h = hb & 7, bb = hb >> 3;
    const int tid = threadIdx.x;
    const int row = tid >> 3;            // 0..31
    const int d0 = (tid & 7) * 8;

    const float l0 = Pml[(size_t)(g * 3 + 0) * 32 + row];
    const float l1 = Pml[(size_t)(g * 3 + 1) * 32 + row];
    const float l2 = Pml[(size_t)(g * 3 + 2) * 32 + row];
    const float inv = 1.0f / (l0 + l1 + l2);
    const float c0 = l0 * inv, c1 = l1 * inv, c2 = l2 * inv;

    const unsigned short* p0 = Po + (size_t)(g * 3 + 0) * 2048 + row * 64 + d0;
    const unsigned short* p1 = p0 + 2048;
    const unsigned short* p2 = p1 + 2048;
    unsigned short sa[8], sb[8], sc[8], so[8];
    *(int4*)&sa[0] = *(const int4*)p0;
    *(int4*)&sb[0] = *(const int4*)p1;
    *(int4*)&sc[0] = *(const int4*)p2;
#pragma unroll
    for (int i = 0; i < 8; ++i) {
        float fa = __uint_as_float((unsigned int)sa[i] << 16);
        float fb = __uint_as_float((unsigned int)sb[i] << 16);
        float fc = __uint_as_float((unsigned int)sc[i] << 16);
        so[i] = f2bf(fa * c0 + fb * c1 + fc * c2);
    }
    unsigned short* dst = attnb + ((size_t)bb * NSEQ + qw * 32 + row) * INNER + h * DH + d0;
    *(int4*)dst = *(const int4*)&so[0];
}

// ---------------------------------------------------------------------------
// GEMM2: attnb[4096,512] @ wot[512,512]^T + bias -> out fp32. 2-phase
// double-buffered pipeline, 128x64 tiles (round-7 version). Unchanged.
// ---------------------------------------------------------------------------
__global__ __launch_bounds__(256) void gemm_out_kernel(
    const unsigned short* __restrict__ A, const unsigned short* __restrict__ Bt,
    const float* __restrict__ bias, float* __restrict__ out)
{
    __shared__ short Smem[24576];            // 48KB: 2 x (A 128x64 | B 64x64)

    const int tid = threadIdx.x;
    const int w = tid >> 6, lane = tid & 63;
    const int lo = lane & 15, quad = lane >> 4;
    const int wm = (w & 1) * 64, wn = (w >> 1) * 32;

    const int l = blockIdx.x;
    const int xcd = l & 7, p = l >> 3;
    const int mi = (xcd >> 1) * 8 + (p >> 2);   // 0..31
    const int ni = (xcd & 1) * 4 + (p & 3);     // 0..7
    const int m0 = mi * 128, n0 = ni * 64;

    f32x4 acc[4][2];
#pragma unroll
    for (int i = 0; i < 4; ++i)
#pragma unroll
        for (int j = 0; j < 2; ++j) acc[i][j] = (f32x4)0.0f;

    auto stage = [&](int buf, int k0) {
        short* SA = Smem + buf * 12288;
        short* SB = SA + 8192;
#pragma unroll
        for (int it = 0; it < 4; ++it) {
            const int idx = it * 2048 + tid * 8;
            gl_lds16(A + (size_t)(m0 + (idx >> 6)) * INNER + k0 + (idx & 63),
                     SA + idx);
        }
#pragma unroll
        for (int it = 0; it < 2; ++it) {
            const int idx = it * 2048 + tid * 8;
            gl_lds16(Bt + (size_t)(n0 + (idx >> 6)) * INNER + k0 + (idx & 63),
                     SB + idx);
        }
    };

    stage(0, 0);
    __syncthreads();
    int cur = 0;
    for (int k0 = 0; k0 < INNER; k0 += 64) {
        if (k0 + 64 < INNER) stage(cur ^ 1, k0 + 64);
        short* SA = Smem + cur * 12288;
        short* SB = SA + 8192;
#pragma unroll
        for (int kc = 0; kc < 2; ++kc) {
            bf16x8 af[4], bf_[2];
#pragma unroll
            for (int mt = 0; mt < 4; ++mt)
                af[mt] = *(const bf16x8*)&SA[(wm + mt * 16 + lo) * 64 + kc * 32 + quad * 8];
#pragma unroll
            for (int nt = 0; nt < 2; ++nt)
                bf_[nt] = *(const bf16x8*)&SB[(wn + nt * 16 + lo) * 64 + kc * 32 + quad * 8];
#pragma unroll
            for (int mt = 0; mt < 4; ++mt)
#pragma unroll
                for (int nt = 0; nt < 2; ++nt)
                    acc[mt][nt] = __builtin_amdgcn_mfma_f32_16x16x32_bf16(
                        af[mt], bf_[nt], acc[mt][nt], 0, 0, 0);
        }
        __syncthreads();
        cur ^= 1;
    }

#pragma unroll
    for (int mt = 0; mt < 4; ++mt) {
        const int gm0 = m0 + wm + mt * 16 + quad * 4;
#pragma unroll
        for (int nt = 0; nt < 2; ++nt) {
            const int gc = n0 + wn + nt * 16 + lo;
            const float b = bias[gc];
#pragma unroll
            for (int r = 0; r < 4; ++r)
                out[(size_t)(gm0 + r) * DMODEL + gc] = acc[mt][nt][r] + b;
        }
    }
}

// ---------------------------------------------------------------------------
extern "C" void kernel_launch(void* const* d_in, const int* in_sizes, int n_in,
                              void* d_out, int out_size, void* d_ws, size_t ws_size,
                              hipStream_t stream) {
    const float* x    = (const float*)d_in[0];
    const float* Wqkv = (const float*)d_in[2];
    const float* Wout = (const float*)d_in[3];
    const float* bout = (const float*)d_in[4];
    float* out = (float*)d_out;

    unsigned short* wsS  = (unsigned short*)d_ws;
    unsigned short* wqt  = wsS;                                  // 768K shorts
    unsigned short* wot  = wqt + (size_t)QKV_COLS * DMODEL;      // 256K
    unsigned short* Qb   = wot + (size_t)DMODEL * INNER;         // 2M
    unsigned short* Kf   = Qb  + (size_t)BDIM * NH * NSEQ * DH;  // 2M
    unsigned short* Vf   = Kf  + (size_t)BDIM * NH * NSEQ * DH;  // 2M
    unsigned short* Po   = Vf  + (size_t)BDIM * NH * NSEQ * DH;  // 6M
    float* Pml = (float*)(Po + (size_t)3072 * 2048);             // 96K floats
    unsigned short* attnb = (unsigned short*)(Pml + 3072 * 32);  // 2M
    unsigned short* Xb   = attnb + (size_t)MROWS * INNER;        // 2M

    conv_all_kernel<<<768, 256, 0, stream>>>(x, Wqkv, Wout, Xb, wqt, wot);
    gemm_qkv_kernel<<<384, 256, 0, stream>>>(Xb, wqt, Qb, Kf, Vf);
    flash_kernel<<<dim3(NH * BDIM, 16, 3), 256, 0, stream>>>(Qb, Kf, Vf, Pml, Po);
    combine_kernel<<<NH * BDIM * 64, 256, 0, stream>>>(Pml, Po, attnb);
    gemm_out_kernel<<<256, 256, 0, stream>>>(attnb, wot, bout, out);
}